// Round 9
// baseline (425.825 us; speedup 1.0000x reference)
//
#include <hip/hip_runtime.h>
#include <hip/hip_bf16.h>
#include <math.h>

#define N 8192
#define D 256
#define EPSF 1e-6f

typedef __attribute__((ext_vector_type(8))) short short8v;
typedef __attribute__((ext_vector_type(4))) float f32x4;
typedef __attribute__((ext_vector_type(4))) unsigned short u16x4;

__device__ __forceinline__ unsigned short f2bf(float x) {
    __hip_bfloat16 h = __float2bfloat16(x);
    return *(unsigned short*)&h;
}
__device__ __forceinline__ float bf2f(unsigned short u) {
    __hip_bfloat16 h = *(__hip_bfloat16*)&u;
    return __bfloat162float(h);
}
__device__ __forceinline__ float bfu2f(unsigned short u) {
    unsigned int x = ((unsigned int)u) << 16;
    float f;
    __builtin_memcpy(&f, &x, 4);
    return f;
}
__device__ __forceinline__ f32x4 ntload4(const float* p) {
    return __builtin_nontemporal_load((const f32x4*)p);
}
__device__ __forceinline__ void ntstore4(float* p, f32x4 v) {
    __builtin_nontemporal_store(v, (f32x4*)p);
}

// async global->LDS, 16B per lane; LDS dest = wave-uniform base + lane*16
// aux = CPol immediate: 0 = normal (cached), 2 = NT (non-temporal / evict-first)
#define GLOAD_LDS16(gp, lp)                                                                  \
    __builtin_amdgcn_global_load_lds((const __attribute__((address_space(1))) unsigned int*)(gp), \
                                     (__attribute__((address_space(3))) unsigned int*)(lp), 16, 0, 0)
#define GLOAD_LDS16NT(gp, lp)                                                                \
    __builtin_amdgcn_global_load_lds((const __attribute__((address_space(1))) unsigned int*)(gp), \
                                     (__attribute__((address_space(3))) unsigned int*)(lp), 16, 0, 2)

// ---------------- split z -> Bh, Bl (bf16 hi/lo) ----------------
__global__ __launch_bounds__(256) void split_kernel(const float* __restrict__ x,
                                                    unsigned short* __restrict__ hi,
                                                    unsigned short* __restrict__ lo) {
    int i = (blockIdx.x * 256 + threadIdx.x) * 4;
    float4 v = *(const float4*)&x[i];
    ushort4 h, l;
    float a;
    a = v.x; h.x = f2bf(a); l.x = f2bf(a - bf2f(h.x));
    a = v.y; h.y = f2bf(a); l.y = f2bf(a - bf2f(h.y));
    a = v.z; h.z = f2bf(a); l.z = f2bf(a - bf2f(h.z));
    a = v.w; h.w = f2bf(a); l.w = f2bf(a - bf2f(h.w));
    *(ushort4*)&hi[i] = h;
    *(ushort4*)&lo[i] = l;
}

// ---------------- zW = z @ W, split to Ah, Al ----------------
__global__ __launch_bounds__(256) void zw_kernel(const float* __restrict__ z,
                                                 const float* __restrict__ W,
                                                 unsigned short* __restrict__ Ah,
                                                 unsigned short* __restrict__ Al) {
    __shared__ float zs[32 * D];
    int rowBase = blockIdx.x * 32;
    const float4* zg = (const float4*)(z + (size_t)rowBase * D);
    float4* zs4 = (float4*)zs;
    for (int i = threadIdx.x; i < 32 * D / 4; i += 256) zs4[i] = zg[i];
    __syncthreads();

    float acc[32];
#pragma unroll
    for (int r = 0; r < 32; ++r) acc[r] = 0.f;
    int col = threadIdx.x;
    for (int kb = 0; kb < D; kb += 4) {
        float w0 = W[(size_t)(kb + 0) * D + col];
        float w1 = W[(size_t)(kb + 1) * D + col];
        float w2 = W[(size_t)(kb + 2) * D + col];
        float w3 = W[(size_t)(kb + 3) * D + col];
#pragma unroll
        for (int r = 0; r < 32; ++r) {
            float4 zv = *(const float4*)&zs[r * D + kb];
            acc[r] = fmaf(zv.x, w0, acc[r]);
            acc[r] = fmaf(zv.y, w1, acc[r]);
            acc[r] = fmaf(zv.z, w2, acc[r]);
            acc[r] = fmaf(zv.w, w3, acc[r]);
        }
    }
#pragma unroll
    for (int r = 0; r < 32; ++r) {
        float a = acc[r];
        unsigned short h = f2bf(a);
        unsigned short l = f2bf(a - bf2f(h));
        Ah[(size_t)(rowBase + r) * D + col] = h;
        Al[(size_t)(rowBase + r) * D + col] = l;
    }
}

// XCD-banded tile mapping (col-major within each XCD's 8-row band)
__device__ __forceinline__ void tile_map(int bid, int& rowBase, int& colBase) {
    int xcd = bid & 7;
    int idx = bid >> 3;
    int bx = idx >> 3;
    int by = xcd * 8 + (idx & 7);
    rowBase = by * 128;
    colBase = bx * 128;
}

// ---------------- Pass A: s = sqrt(relu(sim-beta)+eps), stored bf16 (ws) or f32 (d_out) ----------------
template <bool BF16S>
__global__ __launch_bounds__(256, 4) void gemm_s_kernel(
    const unsigned short* __restrict__ Ah, const unsigned short* __restrict__ Al,
    const unsigned short* __restrict__ Bh, const unsigned short* __restrict__ Bl,
    const float* __restrict__ beta, unsigned short* __restrict__ sbf,
    float* __restrict__ sf32) {
    __shared__ unsigned short lds[4][128][32];  // 32 KB, reused as epilogue scratch

    int rowBase, colBase;
    tile_map(blockIdx.x, rowBase, colBase);

    int t = threadIdx.x;
    int lane = t & 63;
    int w = t >> 6;
    int wr = w >> 1, wc = w & 1;
    int fr = lane & 15;
    int fg = lane >> 4;

    // wave w stages tile w: 0=Ah 1=Al 2=Bh 3=Bl.  A loads cached (band stays L2-resident),
    // B loads non-temporal (streaming panels, evict-first, don't churn the A band).
    const unsigned short* tsrc = (w == 0) ? Ah : (w == 1) ? Al : (w == 2) ? Bh : Bl;
    int tRB = (w < 2) ? rowBase : colBase;
    int slot_src = (lane & 3) ^ ((lane >> 3) & 3);  // swz(r) for r=j*16+(lane>>2) is j-invariant
    const unsigned short* gt = tsrc + (size_t)(tRB + (lane >> 2)) * D + slot_src * 8;

    f32x4 acc[4][4];
#pragma unroll
    for (int m = 0; m < 4; ++m)
#pragma unroll
        for (int n = 0; n < 4; ++n) acc[m][n] = (f32x4){0.f, 0.f, 0.f, 0.f};

    for (int kt = 0; kt < D; kt += 32) {
        __syncthreads();  // prev iter's frag reads done
        if (w < 2) {
#pragma unroll
            for (int j = 0; j < 8; ++j) GLOAD_LDS16(gt + kt + j * 16 * D, &lds[w][j * 16][0]);
        } else {
#pragma unroll
            for (int j = 0; j < 8; ++j) GLOAD_LDS16NT(gt + kt + j * 16 * D, &lds[w][j * 16][0]);
        }
        __syncthreads();  // vmcnt(0) drained before barrier -> tile complete

        short8v bhf[4], blf[4];
#pragma unroll
        for (int n = 0; n < 4; ++n) {
            int row = wc * 64 + n * 16 + fr;
            int sl = fg ^ ((row >> 1) & 3);
            bhf[n] = *(const short8v*)&lds[2][row][sl * 8];
            blf[n] = *(const short8v*)&lds[3][row][sl * 8];
        }
#pragma unroll
        for (int m = 0; m < 4; ++m) {
            int row = wr * 64 + m * 16 + fr;
            int sl = fg ^ ((row >> 1) & 3);
            short8v ahf = *(const short8v*)&lds[0][row][sl * 8];
            short8v alf = *(const short8v*)&lds[1][row][sl * 8];
#pragma unroll
            for (int n = 0; n < 4; ++n) {
                acc[m][n] = __builtin_amdgcn_mfma_f32_16x16x32_bf16(ahf, bhf[n], acc[m][n], 0, 0, 0);
                acc[m][n] = __builtin_amdgcn_mfma_f32_16x16x32_bf16(ahf, blf[n], acc[m][n], 0, 0, 0);
                acc[m][n] = __builtin_amdgcn_mfma_f32_16x16x32_bf16(alf, bhf[n], acc[m][n], 0, 0, 0);
            }
        }
    }

    // epilogue: repack through per-wave LDS scratch -> coalesced nontemporal stores
    __syncthreads();
    float* scratch = (float*)lds + w * (16 * 68);

#pragma unroll
    for (int m = 0; m < 4; ++m) {
#pragma unroll
        for (int n = 0; n < 4; ++n)
#pragma unroll
            for (int reg = 0; reg < 4; ++reg)
                scratch[(fg * 4 + reg) * 68 + n * 16 + fr] = acc[m][n][reg];

#pragma unroll
        for (int sub = 0; sub < 4; ++sub) {
            int rloc = sub * 4 + fg;
            int i = rowBase + wr * 64 + m * 16 + rloc;
            int col = colBase + wc * 64 + fr * 4;
            float4 sv = *(const float4*)&scratch[rloc * 68 + fr * 4];
            float bi = beta[i];
            float s0 = sqrtf(fmaxf(sv.x - bi, 0.f) + EPSF);
            float s1 = sqrtf(fmaxf(sv.y - bi, 0.f) + EPSF);
            float s2 = sqrtf(fmaxf(sv.z - bi, 0.f) + EPSF);
            float s3 = sqrtf(fmaxf(sv.w - bi, 0.f) + EPSF);
            if constexpr (BF16S) {
                u16x4 o = {f2bf(s0), f2bf(s1), f2bf(s2), f2bf(s3)};
                __builtin_nontemporal_store(o, (u16x4*)(sbf + (size_t)i * N + col));
            } else {
                f32x4 o = {s0, s1, s2, s3};
                ntstore4(sf32 + (size_t)i * N + col, o);
            }
        }
        __syncthreads();
    }
}

// ---------------- Pass B: fused row stats + finalize ----------------
template <bool BF16S>
__global__ __launch_bounds__(512) void rownorm_kernel(float* __restrict__ out,
                                                      const float* __restrict__ Q,
                                                      const unsigned short* __restrict__ sbf) {
    __shared__ short8v sb[N / 8];  // 16 KB
    __shared__ short8v qb[N / 8];  // 16 KB
    __shared__ float red[24];

    int row = blockIdx.x;
    int t = threadIdx.x;
    const float* qrow = Q + (size_t)row * N;

    float ps = 0.f, pq = 0.f, qs = 0.f;
    for (int k = t; k < N / 8; k += 512) {
        float s[8];
        short8v spack;
        if constexpr (BF16S) {
            spack = __builtin_nontemporal_load((const short8v*)(sbf + (size_t)row * N + k * 8));
#pragma unroll
            for (int j = 0; j < 8; ++j) s[j] = bfu2f((unsigned short)spack[j]);
        } else {
            f32x4 a = ntload4(out + (size_t)row * N + k * 8);
            f32x4 b = ntload4(out + (size_t)row * N + k * 8 + 4);
            s[0] = a.x; s[1] = a.y; s[2] = a.z; s[3] = a.w;
            s[4] = b.x; s[5] = b.y; s[6] = b.z; s[7] = b.w;
#pragma unroll
            for (int j = 0; j < 8; ++j) spack[j] = (short)f2bf(s[j]);
        }
        sb[k] = spack;
        f32x4 q0 = ntload4(qrow + k * 8);
        f32x4 q1 = ntload4(qrow + k * 8 + 4);
        float q[8] = {q0.x, q0.y, q0.z, q0.w, q1.x, q1.y, q1.z, q1.w};
        short8v qpack;
#pragma unroll
        for (int j = 0; j < 8; ++j) qpack[j] = (short)f2bf(q[j]);
        qb[k] = qpack;
#pragma unroll
        for (int j = 0; j < 8; ++j) {
            ps += s[j];
            pq += s[j] * q[j];
            qs += q[j];
        }
    }
#pragma unroll
    for (int off = 1; off < 64; off <<= 1) {
        ps += __shfl_xor(ps, off, 64);
        pq += __shfl_xor(pq, off, 64);
        qs += __shfl_xor(qs, off, 64);
    }
    if ((t & 63) == 0) {
        int wv = t >> 6;
        red[wv * 3 + 0] = ps;
        red[wv * 3 + 1] = pq;
        red[wv * 3 + 2] = qs;
    }
    __syncthreads();
    float tps = 0.f, tpq = 0.f, tqs = 0.f;
#pragma unroll
    for (int i = 0; i < 8; ++i) {
        tps += red[i * 3 + 0];
        tpq += red[i * 3 + 1];
        tqs += red[i * 3 + 2];
    }
    float sh = 0.5f / tqs;
    float wv = 1.0f / (0.5f * tps + sh * tpq);

    float* orow = out + (size_t)row * N;
    for (int k = t; k < N / 8; k += 512) {
        short8v sp = sb[k];
        short8v qp = qb[k];
        f32x4 o0, o1;
#pragma unroll
        for (int j = 0; j < 4; ++j)
            o0[j] = bfu2f((unsigned short)sp[j]) * fmaf(bfu2f((unsigned short)qp[j]), sh, 0.5f) * wv;
#pragma unroll
        for (int j = 0; j < 4; ++j)
            o1[j] = bfu2f((unsigned short)sp[j + 4]) * fmaf(bfu2f((unsigned short)qp[j + 4]), sh, 0.5f) * wv;
        ntstore4(orow + k * 8, o0);
        ntstore4(orow + k * 8 + 4, o1);
    }
}

extern "C" void kernel_launch(void* const* d_in, const int* in_sizes, int n_in,
                              void* d_out, int out_size, void* d_ws, size_t ws_size,
                              hipStream_t stream) {
    const float* z = (const float*)d_in[0];
    const float* W = (const float*)d_in[1];
    const float* beta = (const float*)d_in[2];
    const float* Q = (const float*)d_in[3];
    float* out = (float*)d_out;

    unsigned short* Ah = (unsigned short*)d_ws;  // N*D bf16 each (4 MB x 4)
    unsigned short* Al = Ah + (size_t)N * D;
    unsigned short* Bh = Al + (size_t)N * D;
    unsigned short* Bl = Bh + (size_t)N * D;
    unsigned short* sbf = Bl + (size_t)N * D;  // N*N bf16 (134 MB) if ws permits

    size_t need = 4 * (size_t)N * D * sizeof(unsigned short) + (size_t)N * N * sizeof(unsigned short);
    bool bf16s = (ws_size >= need);

    split_kernel<<<(N * D / 4) / 256, 256, 0, stream>>>(z, Bh, Bl);
    zw_kernel<<<N / 32, 256, 0, stream>>>(z, W, Ah, Al);
    if (bf16s) {
        gemm_s_kernel<true><<<4096, 256, 0, stream>>>(Ah, Al, Bh, Bl, beta, sbf, nullptr);
        rownorm_kernel<true><<<N, 512, 0, stream>>>(out, Q, sbf);
    } else {
        gemm_s_kernel<false><<<4096, 256, 0, stream>>>(Ah, Al, Bh, Bl, beta, nullptr, out);
        rownorm_kernel<false><<<N, 512, 0, stream>>>(out, Q, nullptr);
    }
}

// Round 10
// 301.747 us; speedup vs baseline: 1.4112x; 1.4112x over previous
//
#include <hip/hip_runtime.h>
#include <hip/hip_bf16.h>
#include <math.h>

#define N 8192
#define D 256
#define EPSF 1e-6f

typedef __attribute__((ext_vector_type(8))) short short8v;
typedef __attribute__((ext_vector_type(4))) float f32x4;
typedef __attribute__((ext_vector_type(4))) unsigned short u16x4;

__device__ __forceinline__ unsigned short f2bf(float x) {
    __hip_bfloat16 h = __float2bfloat16(x);
    return *(unsigned short*)&h;
}
__device__ __forceinline__ float bf2f(unsigned short u) {
    __hip_bfloat16 h = *(__hip_bfloat16*)&u;
    return __bfloat162float(h);
}
__device__ __forceinline__ float bfu2f(unsigned short u) {
    unsigned int x = ((unsigned int)u) << 16;
    float f;
    __builtin_memcpy(&f, &x, 4);
    return f;
}
__device__ __forceinline__ f32x4 ntload4(const float* p) {
    return __builtin_nontemporal_load((const f32x4*)p);
}
__device__ __forceinline__ void ntstore4(float* p, f32x4 v) {
    __builtin_nontemporal_store(v, (f32x4*)p);
}

// async global->LDS, 16B per lane; LDS dest = wave-uniform base + lane*16 (aux=0: normal caching)
#define GLOAD_LDS16(gp, lp)                                                                  \
    __builtin_amdgcn_global_load_lds((const __attribute__((address_space(1))) unsigned int*)(gp), \
                                     (__attribute__((address_space(3))) unsigned int*)(lp), 16, 0, 0)

// ---------------- split z -> Bh, Bl (bf16 hi/lo) ----------------
__global__ __launch_bounds__(256) void split_kernel(const float* __restrict__ x,
                                                    unsigned short* __restrict__ hi,
                                                    unsigned short* __restrict__ lo) {
    int i = (blockIdx.x * 256 + threadIdx.x) * 4;
    float4 v = *(const float4*)&x[i];
    ushort4 h, l;
    float a;
    a = v.x; h.x = f2bf(a); l.x = f2bf(a - bf2f(h.x));
    a = v.y; h.y = f2bf(a); l.y = f2bf(a - bf2f(h.y));
    a = v.z; h.z = f2bf(a); l.z = f2bf(a - bf2f(h.z));
    a = v.w; h.w = f2bf(a); l.w = f2bf(a - bf2f(h.w));
    *(ushort4*)&hi[i] = h;
    *(ushort4*)&lo[i] = l;
}

// ---------------- zW = z @ W, split to Ah, Al ----------------
__global__ __launch_bounds__(256) void zw_kernel(const float* __restrict__ z,
                                                 const float* __restrict__ W,
                                                 unsigned short* __restrict__ Ah,
                                                 unsigned short* __restrict__ Al) {
    __shared__ float zs[32 * D];
    int rowBase = blockIdx.x * 32;
    const float4* zg = (const float4*)(z + (size_t)rowBase * D);
    float4* zs4 = (float4*)zs;
    for (int i = threadIdx.x; i < 32 * D / 4; i += 256) zs4[i] = zg[i];
    __syncthreads();

    float acc[32];
#pragma unroll
    for (int r = 0; r < 32; ++r) acc[r] = 0.f;
    int col = threadIdx.x;
    for (int kb = 0; kb < D; kb += 4) {
        float w0 = W[(size_t)(kb + 0) * D + col];
        float w1 = W[(size_t)(kb + 1) * D + col];
        float w2 = W[(size_t)(kb + 2) * D + col];
        float w3 = W[(size_t)(kb + 3) * D + col];
#pragma unroll
        for (int r = 0; r < 32; ++r) {
            float4 zv = *(const float4*)&zs[r * D + kb];
            acc[r] = fmaf(zv.x, w0, acc[r]);
            acc[r] = fmaf(zv.y, w1, acc[r]);
            acc[r] = fmaf(zv.z, w2, acc[r]);
            acc[r] = fmaf(zv.w, w3, acc[r]);
        }
    }
#pragma unroll
    for (int r = 0; r < 32; ++r) {
        float a = acc[r];
        unsigned short h = f2bf(a);
        unsigned short l = f2bf(a - bf2f(h));
        Ah[(size_t)(rowBase + r) * D + col] = h;
        Al[(size_t)(rowBase + r) * D + col] = l;
    }
}

// XCD-banded tile mapping (col-major within each XCD's 8-row band)
__device__ __forceinline__ void tile_map(int bid, int& rowBase, int& colBase) {
    int xcd = bid & 7;
    int idx = bid >> 3;
    int bx = idx >> 3;
    int by = xcd * 8 + (idx & 7);
    rowBase = by * 128;
    colBase = bx * 128;
}

// ---------------- Pass A: s = sqrt(relu(sim-beta)+eps), stored bf16 (ws) or f32 (d_out) ----------------
// Pipelined single-buffer: read frags(t) -> barrier -> issue stage(t+1) -> MFMA(t).
// The compiler's vmcnt(0) drain lands at the NEXT iteration's top barrier, so the
// staging loads overlap the 48-MFMA phase instead of being serially exposed.
template <bool BF16S>
__global__ __launch_bounds__(256, 3) void gemm_s_kernel(
    const unsigned short* __restrict__ Ah, const unsigned short* __restrict__ Al,
    const unsigned short* __restrict__ Bh, const unsigned short* __restrict__ Bl,
    const float* __restrict__ beta, unsigned short* __restrict__ sbf,
    float* __restrict__ sf32) {
    __shared__ unsigned short lds[4][128][32];  // 32 KB, reused as epilogue scratch

    int rowBase, colBase;
    tile_map(blockIdx.x, rowBase, colBase);

    int t = threadIdx.x;
    int lane = t & 63;
    int w = t >> 6;
    int wr = w >> 1, wc = w & 1;
    int fr = lane & 15;
    int fg = lane >> 4;

    // wave w stages tile w: 0=Ah 1=Al 2=Bh 3=Bl
    const unsigned short* tsrc = (w == 0) ? Ah : (w == 1) ? Al : (w == 2) ? Bh : Bl;
    int tRB = (w < 2) ? rowBase : colBase;
    int slot_src = (lane & 3) ^ ((lane >> 3) & 3);  // swz(r) for r=j*16+(lane>>2) is j-invariant
    const unsigned short* gt = tsrc + (size_t)(tRB + (lane >> 2)) * D + slot_src * 8;

    f32x4 acc[4][4];
#pragma unroll
    for (int m = 0; m < 4; ++m)
#pragma unroll
        for (int n = 0; n < 4; ++n) acc[m][n] = (f32x4){0.f, 0.f, 0.f, 0.f};

    // prologue: stage tile kt=0
#pragma unroll
    for (int j = 0; j < 8; ++j) GLOAD_LDS16(gt + j * 16 * D, &lds[w][j * 16][0]);

    for (int kt = 0; kt < D; kt += 32) {
        __syncthreads();  // drains vmcnt(0): staged tile (issued last iter / prologue) complete

        short8v ahf[4], alf[4], bhf[4], blf[4];
#pragma unroll
        for (int n = 0; n < 4; ++n) {
            int row = wc * 64 + n * 16 + fr;
            int sl = fg ^ ((row >> 1) & 3);
            bhf[n] = *(const short8v*)&lds[2][row][sl * 8];
            blf[n] = *(const short8v*)&lds[3][row][sl * 8];
        }
#pragma unroll
        for (int m = 0; m < 4; ++m) {
            int row = wr * 64 + m * 16 + fr;
            int sl = fg ^ ((row >> 1) & 3);
            ahf[m] = *(const short8v*)&lds[0][row][sl * 8];
            alf[m] = *(const short8v*)&lds[1][row][sl * 8];
        }
        __syncthreads();  // all waves hold frags in regs; LDS free for restage (lgkm drained here)

        if (kt + 32 < D) {
#pragma unroll
            for (int j = 0; j < 8; ++j)
                GLOAD_LDS16(gt + kt + 32 + j * 16 * D, &lds[w][j * 16][0]);
        }
        __builtin_amdgcn_sched_barrier(0);  // pin: loads issued before the MFMA cluster

#pragma unroll
        for (int m = 0; m < 4; ++m)
#pragma unroll
            for (int n = 0; n < 4; ++n) {
                acc[m][n] = __builtin_amdgcn_mfma_f32_16x16x32_bf16(ahf[m], bhf[n], acc[m][n], 0, 0, 0);
                acc[m][n] = __builtin_amdgcn_mfma_f32_16x16x32_bf16(ahf[m], blf[n], acc[m][n], 0, 0, 0);
                acc[m][n] = __builtin_amdgcn_mfma_f32_16x16x32_bf16(alf[m], bhf[n], acc[m][n], 0, 0, 0);
            }
    }

    // epilogue: repack through per-wave LDS scratch -> coalesced nontemporal stores
    __syncthreads();
    float* scratch = (float*)lds + w * (16 * 68);

#pragma unroll
    for (int m = 0; m < 4; ++m) {
#pragma unroll
        for (int n = 0; n < 4; ++n)
#pragma unroll
            for (int reg = 0; reg < 4; ++reg)
                scratch[(fg * 4 + reg) * 68 + n * 16 + fr] = acc[m][n][reg];

#pragma unroll
        for (int sub = 0; sub < 4; ++sub) {
            int rloc = sub * 4 + fg;
            int i = rowBase + wr * 64 + m * 16 + rloc;
            int col = colBase + wc * 64 + fr * 4;
            float4 sv = *(const float4*)&scratch[rloc * 68 + fr * 4];
            float bi = beta[i];
            float s0 = sqrtf(fmaxf(sv.x - bi, 0.f) + EPSF);
            float s1 = sqrtf(fmaxf(sv.y - bi, 0.f) + EPSF);
            float s2 = sqrtf(fmaxf(sv.z - bi, 0.f) + EPSF);
            float s3 = sqrtf(fmaxf(sv.w - bi, 0.f) + EPSF);
            if constexpr (BF16S) {
                u16x4 o = {f2bf(s0), f2bf(s1), f2bf(s2), f2bf(s3)};
                __builtin_nontemporal_store(o, (u16x4*)(sbf + (size_t)i * N + col));
            } else {
                f32x4 o = {s0, s1, s2, s3};
                ntstore4(sf32 + (size_t)i * N + col, o);
            }
        }
        __syncthreads();
    }
}

// ---------------- Pass B: fused row stats + finalize ----------------
template <bool BF16S>
__global__ __launch_bounds__(512) void rownorm_kernel(float* __restrict__ out,
                                                      const float* __restrict__ Q,
                                                      const unsigned short* __restrict__ sbf) {
    __shared__ short8v sb[N / 8];  // 16 KB
    __shared__ short8v qb[N / 8];  // 16 KB
    __shared__ float red[24];

    int row = blockIdx.x;
    int t = threadIdx.x;
    const float* qrow = Q + (size_t)row * N;

    float ps = 0.f, pq = 0.f, qs = 0.f;
    for (int k = t; k < N / 8; k += 512) {
        float s[8];
        short8v spack;
        if constexpr (BF16S) {
            spack = __builtin_nontemporal_load((const short8v*)(sbf + (size_t)row * N + k * 8));
#pragma unroll
            for (int j = 0; j < 8; ++j) s[j] = bfu2f((unsigned short)spack[j]);
        } else {
            f32x4 a = ntload4(out + (size_t)row * N + k * 8);
            f32x4 b = ntload4(out + (size_t)row * N + k * 8 + 4);
            s[0] = a.x; s[1] = a.y; s[2] = a.z; s[3] = a.w;
            s[4] = b.x; s[5] = b.y; s[6] = b.z; s[7] = b.w;
#pragma unroll
            for (int j = 0; j < 8; ++j) spack[j] = (short)f2bf(s[j]);
        }
        sb[k] = spack;
        f32x4 q0 = ntload4(qrow + k * 8);
        f32x4 q1 = ntload4(qrow + k * 8 + 4);
        float q[8] = {q0.x, q0.y, q0.z, q0.w, q1.x, q1.y, q1.z, q1.w};
        short8v qpack;
#pragma unroll
        for (int j = 0; j < 8; ++j) qpack[j] = (short)f2bf(q[j]);
        qb[k] = qpack;
#pragma unroll
        for (int j = 0; j < 8; ++j) {
            ps += s[j];
            pq += s[j] * q[j];
            qs += q[j];
        }
    }
#pragma unroll
    for (int off = 1; off < 64; off <<= 1) {
        ps += __shfl_xor(ps, off, 64);
        pq += __shfl_xor(pq, off, 64);
        qs += __shfl_xor(qs, off, 64);
    }
    if ((t & 63) == 0) {
        int wv = t >> 6;
        red[wv * 3 + 0] = ps;
        red[wv * 3 + 1] = pq;
        red[wv * 3 + 2] = qs;
    }
    __syncthreads();
    float tps = 0.f, tpq = 0.f, tqs = 0.f;
#pragma unroll
    for (int i = 0; i < 8; ++i) {
        tps += red[i * 3 + 0];
        tpq += red[i * 3 + 1];
        tqs += red[i * 3 + 2];
    }
    float sh = 0.5f / tqs;
    float wv = 1.0f / (0.5f * tps + sh * tpq);

    float* orow = out + (size_t)row * N;
    for (int k = t; k < N / 8; k += 512) {
        short8v sp = sb[k];
        short8v qp = qb[k];
        f32x4 o0, o1;
#pragma unroll
        for (int j = 0; j < 4; ++j)
            o0[j] = bfu2f((unsigned short)sp[j]) * fmaf(bfu2f((unsigned short)qp[j]), sh, 0.5f) * wv;
#pragma unroll
        for (int j = 0; j < 4; ++j)
            o1[j] = bfu2f((unsigned short)sp[j + 4]) * fmaf(bfu2f((unsigned short)qp[j + 4]), sh, 0.5f) * wv;
        ntstore4(orow + k * 8, o0);
        ntstore4(orow + k * 8 + 4, o1);
    }
}

extern "C" void kernel_launch(void* const* d_in, const int* in_sizes, int n_in,
                              void* d_out, int out_size, void* d_ws, size_t ws_size,
                              hipStream_t stream) {
    const float* z = (const float*)d_in[0];
    const float* W = (const float*)d_in[1];
    const float* beta = (const float*)d_in[2];
    const float* Q = (const float*)d_in[3];
    float* out = (float*)d_out;

    unsigned short* Ah = (unsigned short*)d_ws;  // N*D bf16 each (4 MB x 4)
    unsigned short* Al = Ah + (size_t)N * D;
    unsigned short* Bh = Al + (size_t)N * D;
    unsigned short* Bl = Bh + (size_t)N * D;
    unsigned short* sbf = Bl + (size_t)N * D;  // N*N bf16 (134 MB) if ws permits

    size_t need = 4 * (size_t)N * D * sizeof(unsigned short) + (size_t)N * N * sizeof(unsigned short);
    bool bf16s = (ws_size >= need);

    split_kernel<<<(N * D / 4) / 256, 256, 0, stream>>>(z, Bh, Bl);
    zw_kernel<<<N / 32, 256, 0, stream>>>(z, W, Ah, Al);
    if (bf16s) {
        gemm_s_kernel<true><<<4096, 256, 0, stream>>>(Ah, Al, Bh, Bl, beta, sbf, nullptr);
        rownorm_kernel<true><<<N, 512, 0, stream>>>(out, Q, sbf);
    } else {
        gemm_s_kernel<false><<<4096, 256, 0, stream>>>(Ah, Al, Bh, Bl, beta, nullptr, out);
        rownorm_kernel<false><<<N, 512, 0, stream>>>(out, Q, nullptr);
    }
}